// Round 2
// baseline (23907.373 us; speedup 1.0000x reference)
//
#include <hip/hip_runtime.h>
#include <math.h>
#include <stddef.h>

#define BB 256
#define TT 512
#define IND 256
#define HH 1024
#define OUTD 256

// ---------------------------------------------------------------------------
// step_gemm: partial projections for one timestep.
// Virtual K = 1280: k in [0,256) -> x[b,t,k]; k in [256,1280) -> h_prev[b,k-256]
// grid (4 b-tiles x 16 j-tiles x 4 k-chunks of 320), block 256.
// Writes P[kchunk][gate][b][j] partial sums (no bias).
// n-gate x-part must stay separate from h-part (r multiplies only h_n+bh_n),
// so chunk 0 accumulates its h-tail (k 256..319) into Pnh instead of P[0][2].
// ---------------------------------------------------------------------------
#define INNER(ACC2)                                                            \
  _Pragma("unroll 8")                                                          \
  for (int c = 0; c < 32; ++c) {                                               \
    const float4 a  = *reinterpret_cast<const float4*>(&As[c][tb4]);           \
    const float4 w0 = *reinterpret_cast<const float4*>(&Ws[0][c][tj4]);        \
    const float4 w1 = *reinterpret_cast<const float4*>(&Ws[1][c][tj4]);        \
    const float4 w2 = *reinterpret_cast<const float4*>(&Ws[2][c][tj4]);        \
    const float av[4]  = {a.x, a.y, a.z, a.w};                                 \
    const float w0v[4] = {w0.x, w0.y, w0.z, w0.w};                             \
    const float w1v[4] = {w1.x, w1.y, w1.z, w1.w};                             \
    const float w2v[4] = {w2.x, w2.y, w2.z, w2.w};                             \
    _Pragma("unroll") for (int i = 0; i < 4; ++i) {                            \
      _Pragma("unroll") for (int l = 0; l < 4; ++l) {                          \
        acc[0][i][l] += av[i] * w0v[l];                                        \
        acc[1][i][l] += av[i] * w1v[l];                                        \
        ACC2[i][l]   += av[i] * w2v[l];                                        \
      }                                                                        \
    }                                                                          \
  }

__global__ __launch_bounds__(256) void step_gemm(
    const float* __restrict__ x, const float* __restrict__ Wx,
    const float* __restrict__ Wh, const float* __restrict__ h_prev,
    float* __restrict__ P, float* __restrict__ Pnh, int t)
{
  __shared__ float As[32][68];
  __shared__ float Ws[3][32][68];
  const int tid = threadIdx.x;
  const int b0 = blockIdx.x * 64;
  const int j0 = blockIdx.y * 64;
  const int z  = blockIdx.z;
  const int kg0 = z * 320;

  float acc[3][4][4] = {};
  float accnh[4][4]  = {};

  const int tj4 = (tid & 15) * 4;
  const int tb4 = (tid >> 4) * 4;

  const int a_row = tid >> 3;          // 0..31
  const int a_c4  = (tid & 7) * 4;     // 0,4,...,28

  for (int s = 0; s < 10; ++s) {
    const int kg = kg0 + s * 32;
    const bool isx = (kg < 256);
    __syncthreads();
    // stage A tile (64 b x 32 k, transposed into As[k][b])
    #pragma unroll
    for (int rr = 0; rr < 64; rr += 32) {
      const int b = b0 + a_row + rr;
      float4 v;
      if (isx) v = *reinterpret_cast<const float4*>(
                     &x[((size_t)b * TT + t) * IND + kg + a_c4]);
      else     v = *reinterpret_cast<const float4*>(
                     &h_prev[(size_t)b * HH + (kg - 256) + a_c4]);
      As[a_c4 + 0][a_row + rr] = v.x;
      As[a_c4 + 1][a_row + rr] = v.y;
      As[a_c4 + 2][a_row + rr] = v.z;
      As[a_c4 + 3][a_row + rr] = v.w;
    }
    // stage W tiles (3 gates x 64 j x 32 k, transposed into Ws[g][k][j])
    #pragma unroll
    for (int p = 0; p < 6; ++p) {
      const int f   = tid + 256 * p;
      const int row = f >> 3;          // 0..191
      const int c4  = (f & 7) * 4;
      const int g   = row >> 6;
      const int jj  = row & 63;
      const int j   = j0 + jj;
      float4 v;
      if (isx) v = *reinterpret_cast<const float4*>(
                     &Wx[((size_t)g * HH + j) * IND + kg + c4]);
      else     v = *reinterpret_cast<const float4*>(
                     &Wh[((size_t)g * HH + j) * HH + (kg - 256) + c4]);
      Ws[g][c4 + 0][jj] = v.x;
      Ws[g][c4 + 1][jj] = v.y;
      Ws[g][c4 + 2][jj] = v.z;
      Ws[g][c4 + 3][jj] = v.w;
    }
    __syncthreads();

    const bool use_nh = (!isx) && (z == 0);
    if (use_nh) { INNER(accnh) } else { INNER(acc[2]) }
  }

  // write partials
  const size_t plane = (size_t)BB * HH;
  const int jout = j0 + tj4;
  #pragma unroll
  for (int g = 0; g < 3; ++g) {
    #pragma unroll
    for (int i = 0; i < 4; ++i) {
      const int b = b0 + tb4 + i;
      float4 v = {acc[g][i][0], acc[g][i][1], acc[g][i][2], acc[g][i][3]};
      *reinterpret_cast<float4*>(
        &P[((size_t)(z * 3 + g)) * plane + (size_t)b * HH + jout]) = v;
    }
  }
  if (z == 0) {
    #pragma unroll
    for (int i = 0; i < 4; ++i) {
      const int b = b0 + tb4 + i;
      float4 v = {accnh[i][0], accnh[i][1], accnh[i][2], accnh[i][3]};
      *reinterpret_cast<float4*>(&Pnh[(size_t)b * HH + jout]) = v;
    }
  }
}

// ---------------------------------------------------------------------------
// gate_kernel: reduce K-chunk partials, add biases, apply GRU gating.
// ---------------------------------------------------------------------------
__global__ __launch_bounds__(256) void gate_kernel(
    const float* __restrict__ P, const float* __restrict__ Pnh,
    const float* __restrict__ bx, const float* __restrict__ bh,
    const float* __restrict__ h_prev, float* __restrict__ h_next)
{
  const int cell = blockIdx.x * 256 + threadIdx.x;   // 0..262143
  const int j = cell & (HH - 1);
  const size_t bj = (size_t)cell;
  const size_t plane = (size_t)BB * HH;

  float sr = bx[j] + bh[j];
  float sz = bx[HH + j] + bh[HH + j];
  #pragma unroll
  for (int k = 0; k < 4; ++k) {
    sr += P[((size_t)(k * 3 + 0)) * plane + bj];
    sz += P[((size_t)(k * 3 + 1)) * plane + bj];
  }
  float xn = P[2 * plane + bj] + bx[2 * HH + j];      // k=0,g=2 : x-part only
  float hn = Pnh[bj] + bh[2 * HH + j];
  #pragma unroll
  for (int k = 1; k < 4; ++k) hn += P[((size_t)(k * 3 + 2)) * plane + bj];

  const float r  = 1.f / (1.f + __expf(-sr));
  const float zz = 1.f / (1.f + __expf(-sz));
  const float n  = tanhf(xn + r * hn);
  const float hp = h_prev[bj];
  h_next[bj] = (1.f - zz) * hp + zz * n;
}

// ---------------------------------------------------------------------------
// final_gemm: out[b,o] = h[b,:] . Wf[o,:] + bf[o]    (256x256, runs once)
// ---------------------------------------------------------------------------
__global__ __launch_bounds__(256) void final_gemm(
    const float* __restrict__ h, const float* __restrict__ Wf,
    const float* __restrict__ bf, float* __restrict__ out)
{
  __shared__ float As[32][36];
  __shared__ float Ws[32][36];
  const int tid = threadIdx.x;
  const int b0 = blockIdx.x * 32, o0 = blockIdx.y * 32;
  const int to = tid & 31, tb = tid >> 5;   // tb 0..7
  float acc[4] = {};
  for (int kc = 0; kc < HH; kc += 32) {
    __syncthreads();
    #pragma unroll
    for (int p = 0; p < 4; ++p) {
      const int f = tid + 256 * p;
      const int row = f >> 5, c = f & 31;
      As[c][row] = h[(size_t)(b0 + row) * HH + kc + c];
      Ws[c][row] = Wf[(size_t)(o0 + row) * HH + kc + c];
    }
    __syncthreads();
    #pragma unroll
    for (int c = 0; c < 32; ++c) {
      const float4 a = *reinterpret_cast<const float4*>(&As[c][tb * 4]);
      const float w = Ws[c][to];
      acc[0] += a.x * w; acc[1] += a.y * w; acc[2] += a.z * w; acc[3] += a.w * w;
    }
  }
  #pragma unroll
  for (int i = 0; i < 4; ++i)
    out[(size_t)(b0 + tb * 4 + i) * OUTD + o0 + to] = acc[i] + bf[o0 + to];
}

__global__ void zero_h(float* __restrict__ h)
{
  const int i = blockIdx.x * 256 + threadIdx.x;
  reinterpret_cast<float4*>(h)[i] = float4{0.f, 0.f, 0.f, 0.f};
}

// ---------------------------------------------------------------------------
extern "C" void kernel_launch(void* const* d_in, const int* in_sizes, int n_in,
                              void* d_out, int out_size, void* d_ws, size_t ws_size,
                              hipStream_t stream)
{
  const float* x  = (const float*)d_in[0];
  const float* Wx = (const float*)d_in[1];
  const float* bx = (const float*)d_in[2];
  const float* Wh = (const float*)d_in[3];
  const float* bh = (const float*)d_in[4];
  const float* Wf = (const float*)d_in[5];
  const float* bf = (const float*)d_in[6];
  float* out = (float*)d_out;

  float* ws = (float*)d_ws;
  const size_t plane = (size_t)BB * HH;       // 262144 floats
  float* h0  = ws;
  float* h1  = ws + plane;
  float* P   = ws + 2 * plane;                // 12 planes
  float* Pnh = ws + 14 * plane;               // 1 plane; total 15 planes ~15.7MB

  zero_h<<<256, 256, 0, stream>>>(h0);

  float* cur = h0;
  float* nxt = h1;
  for (int t = 0; t < TT; ++t) {
    step_gemm<<<dim3(4, 16, 4), 256, 0, stream>>>(x, Wx, Wh, cur, P, Pnh, t);
    gate_kernel<<<dim3(1024), 256, 0, stream>>>(P, Pnh, bx, bh, cur, nxt);
    float* tmp = cur; cur = nxt; nxt = tmp;
  }
  final_gemm<<<dim3(8, 8), 256, 0, stream>>>(cur, Wf, bf, out);
}